// Round 17
// baseline (83.450 us; speedup 1.0000x reference)
//
#include <hip/hip_runtime.h>
#include <math.h>

#define N_NODES 50000
#define IN_CH   128
#define TOT_CH  128          // HEADS*OUT_CH
#define NEDGE   800000
#define ETOT    (NEDGE + N_NODES)
#define MTILES  ((N_NODES + 63) / 64)     // 782
#define NBUCK   ((N_NODES + 255) / 256)   // 196 buckets of 256 nodes
#define BCAP    8192                       // fixed slots per bucket (mean 4352, sigma 66)
#define EPB     4096                       // edges per binning block
#define NBIN    ((ETOT + EPB - 1) / EPB)   // 208

// ---------------- workspace layout (bytes) ----------------
#define OFF_XL      ((size_t)0)                 // bf16 [N][128] = 12.8MB
#define OFF_EBUF    ((size_t)12800000)          // u32 [NBUCK*BCAP] = 6.42MB
#define OFF_XR      ((size_t)25600000)          // bf16 [N][128] = 12.8MB
#define OFF_SRC     ((size_t)38400000)          // int [NBUCK*BCAP] = 6.42MB
#define OFF_BT      ((size_t)44900352)          // Bt bf16-pairs 64KB
#define OFF_GCUR    ((size_t)45000064)          // int [NBUCK]
#define OFF_ROWPTR  ((size_t)51200000)          // int2 [N] = 400KB

typedef float f32x4 __attribute__((ext_vector_type(4)));
typedef short s16x8 __attribute__((ext_vector_type(8)));

__device__ __forceinline__ unsigned f2bf(float f) {   // RNE f32->bf16 bits
    unsigned u = __float_as_uint(f);
    return (u + 0x7fffu + ((u >> 16) & 1u)) >> 16;
}
__device__ __forceinline__ float bflo(unsigned u) { return __uint_as_float(u << 16); }
__device__ __forceinline__ float bfhi(unsigned u) { return __uint_as_float(u & 0xffff0000u); }

__device__ __forceinline__ int SWZ(int row, int byteoff) {
    return row * 256 + (byteoff ^ ((row & 7) << 4));
}

// ============ K0: zero gcur ============
__global__ __launch_bounds__(256) void zero_kernel(int* __restrict__ gcur) {
    if (threadIdx.x < NBUCK) gcur[threadIdx.x] = 0;
}

// ============ K1: binscatter (fixed-capacity buckets) || wconv ============
__global__ __launch_bounds__(256) void k1_kernel(
    const float* __restrict__ Wl, const float* __restrict__ Wr,
    unsigned* __restrict__ btg, const int* __restrict__ ei,
    int* __restrict__ gcur, unsigned* __restrict__ ebuf)
{
    __shared__ int lcnt[256];
    __shared__ int lbase[256];
    const int bid = blockIdx.x;
    const int tid = threadIdx.x;

    if (bid < NBIN) {
        lcnt[tid] = 0;
        __syncthreads();
        const int base = bid * EPB;
        int sv[16], dv[16];
#pragma unroll
        for (int u = 0; u < 16; ++u) {
            const int e = base + u * 256 + tid;
            int s32 = 0, d32 = -1;
            if (e < ETOT) {
                if (e < NEDGE) { s32 = ei[e]; d32 = ei[NEDGE + e]; }
                else           { s32 = d32 = e - NEDGE; }
                atomicAdd(&lcnt[d32 >> 8], 1);
            }
            sv[u] = s32; dv[u] = d32;
        }
        __syncthreads();
        if (tid < NBUCK) {
            const int v = lcnt[tid];
            lbase[tid] = v ? atomicAdd(&gcur[tid], v) : 0;
        }
        __syncthreads();
        lcnt[tid] = 0;
        __syncthreads();
#pragma unroll
        for (int u = 0; u < 16; ++u) {
            const int d32 = dv[u];
            if (d32 >= 0) {
                const int b = d32 >> 8;
                const int p = lbase[b] + atomicAdd(&lcnt[b], 1);
                ebuf[b * BCAP + p] = (unsigned)sv[u] | ((unsigned)(d32 & 255) << 16);
            }
        }
    } else {
        const int g = (bid - NBIN) * 256 + tid;
        if (g < 256 * 64) {
            const int n = g >> 6, kk = g & 63;
            const float* W = (n < 128) ? Wl : Wr;
            const int nc = n & 127;
            const float a = W[(size_t)(2 * kk) * 128 + nc];
            const float b = W[(size_t)(2 * kk + 1) * 128 + nc];
            btg[g] = f2bf(a) | (f2bf(b) << 16);
        }
    }
}

// ============ K2: place || MFMA GEMM (x read ONCE; n-loop inside block) ============
__global__ __launch_bounds__(256) void k2_kernel(
    const float* __restrict__ x, const unsigned* __restrict__ btg,
    unsigned* __restrict__ xl_bf, unsigned* __restrict__ xr_bf,
    const unsigned* __restrict__ ebuf, const int* __restrict__ gcur,
    int2* __restrict__ rowptr2, int* __restrict__ ssrc)
{
    __shared__ __align__(16) unsigned char smem[32768];
    __shared__ int wsum[4];
    const int bid = blockIdx.x;
    const int tid = threadIdx.x;

    if (bid < NBUCK) {
        // ---- place: derive node ranges within padded bucket region ----
        int* lcnt = (int*)smem;          // [256]
        int* lcur = ((int*)smem) + 256;  // [256]
        const int ecnt  = gcur[bid];
        const int ebase = bid * BCAP;
        lcnt[tid] = 0;
        __syncthreads();
        for (int k = tid; k < ecnt; k += 256)
            atomicAdd(&lcnt[(ebuf[ebase + k] >> 16) & 255], 1);
        __syncthreads();
        const int lane = tid & 63, wid = tid >> 6;
        const int v = lcnt[tid];
        int s = v;
#pragma unroll
        for (int off = 1; off < 64; off <<= 1) {
            int t = __shfl_up(s, off);
            if (lane >= off) s += t;
        }
        if (lane == 63) wsum[wid] = s;
        __syncthreads();
        if (tid == 0) {
            int acc = 0;
#pragma unroll
            for (int w = 0; w < 4; ++w) { int t = wsum[w]; wsum[w] = acc; acc += t; }
        }
        __syncthreads();
        const int gpos = ebase + wsum[wid] + s - v;   // exclusive prefix in bucket
        const int node = (bid << 8) + tid;
        if (node < N_NODES) rowptr2[node] = make_int2(gpos, gpos + v);
        lcur[tid] = gpos;
        __syncthreads();
        for (int k = tid; k < ecnt; k += 256) {
            const unsigned ed = ebuf[ebase + k];
            const int p = atomicAdd(&lcur[(ed >> 16) & 255], 1);
            ssrc[p] = (int)(ed & 0xffffu);
        }
        return;
    }

    // ---- gemm: one 64-row m-tile; loop over 4 n-subtiles (x staged ONCE) ----
    unsigned char* Al = smem;            // 16KB
    unsigned char* Bl = smem + 16384;    // 16KB (re-staged per n-tile)
    const int mt = bid - NBUCK;
    const int mbase = mt * 64;
    const int l  = tid & 63;
    const int wv = tid >> 6;

    {   // stage A (f32 -> bf16, swizzled) -- once
        const int r = tid >> 2, q = tid & 3;
        int gm = mbase + r;
        gm = (gm < N_NODES) ? gm : (N_NODES - 1);
        const float* xrow = x + (size_t)gm * IN_CH + q * 32;
#pragma unroll
        for (int i = 0; i < 8; ++i) {
            const float4 xv = *(const float4*)(xrow + i * 4);
            uint2 p;
            p.x = f2bf(xv.x) | (f2bf(xv.y) << 16);
            p.y = f2bf(xv.z) | (f2bf(xv.w) << 16);
            *(uint2*)(Al + SWZ(r, q * 64 + i * 8)) = p;
        }
    }
    {   // stage B tile 0
        const int r = tid >> 2, q = tid & 3;
        const unsigned* brow = btg + (size_t)r * 64 + q * 16;
#pragma unroll
        for (int i = 0; i < 4; ++i) {
            const uint4 v = *(const uint4*)(brow + i * 4);
            *(uint4*)(Bl + SWZ(r, q * 64 + i * 16)) = v;
        }
    }
    __syncthreads();

    s16x8 af[4];
#pragma unroll
    for (int ks = 0; ks < 4; ++ks)
        af[ks] = *(const s16x8*)(Al + SWZ(wv * 16 + (l & 15), ks * 64 + (l >> 4) * 16));

    for (int nt4 = 0; nt4 < 4; ++nt4) {
        f32x4 acc[4];
#pragma unroll
        for (int n = 0; n < 4; ++n) acc[n] = (f32x4){0.f, 0.f, 0.f, 0.f};
#pragma unroll
        for (int nsub = 0; nsub < 4; ++nsub) {
#pragma unroll
            for (int ks = 0; ks < 4; ++ks) {
                const s16x8 bfr = *(const s16x8*)(Bl + SWZ(nsub * 16 + (l & 15), ks * 64 + (l >> 4) * 16));
                acc[nsub] = __builtin_amdgcn_mfma_f32_16x16x32_bf16(af[ks], bfr, acc[nsub], 0, 0, 0);
            }
        }
        // epilogue for this 64-col tile
        unsigned* dstbuf = (nt4 < 2) ? xl_bf : xr_bf;
        const int ncol0 = (nt4 & 1) * 64;
#pragma unroll
        for (int nsub = 0; nsub < 4; ++nsub) {
            const int n = ncol0 + nsub * 16 + (l & 15);
#pragma unroll
            for (int reg = 0; reg < 4; ++reg) {
                const float v  = acc[nsub][reg];
                const float vp = __shfl_xor(v, 1);
                const int row = mbase + wv * 16 + (l >> 4) * 4 + reg;
                if (((l & 1) == 0) && row < N_NODES)
                    dstbuf[(size_t)row * 64 + (n >> 1)] = f2bf(v) | (f2bf(vp) << 16);
            }
        }
        if (nt4 == 3) break;
        __syncthreads();   // all waves done reading Bl
        {   // stage B tile nt4+1
            const int r = tid >> 2, q = tid & 3;
            const unsigned* brow = btg + (size_t)((nt4 + 1) * 64 + r) * 64 + q * 16;
#pragma unroll
            for (int i = 0; i < 4; ++i) {
                const uint4 v = *(const uint4*)(brow + i * 4);
                *(uint4*)(Bl + SWZ(r, q * 64 + i * 16)) = v;
            }
        }
        __syncthreads();
    }
}

// ================= K3: fused attention + aggregate =========
// ONE NODE PER QUARTER-WAVE: lane sl holds 8 channels of its quarter's node;
// per iteration the wave gathers 4 rows (one per node) in one VMEM inst.
// ~21 iterations/wave -> 2-deep gather pipeline hides L2/L3 latency.
// No cross-quarter combine, no masked tail (per-lane exec mask does it).
#define DPP_ADD(s, ctrl) do { \
        int _t = __builtin_amdgcn_update_dpp(0, __float_as_int(s), ctrl, 0xf, 0xf, true); \
        s += __int_as_float(_t); } while(0)

__global__ __launch_bounds__(256) void gat_kernel(
    const unsigned* __restrict__ xl_bf, const unsigned* __restrict__ xr_bf,
    const int2* __restrict__ rowptr2, const int* __restrict__ srcs,
    const float* __restrict__ att, const float* __restrict__ bias,
    float* __restrict__ out)
{
    const int l  = threadIdx.x & 63;
    const int wv = threadIdx.x >> 6;
    const int sl = l & 15;                       // channel-group lane
    const int q  = l >> 4;                       // quarter = node slot
    const int i  = blockIdx.x * 16 + wv * 4 + q; // this quarter's node (grid exact)
    const int c8 = sl * 8;
    const float LOG2E = 1.4426950408889634f;
    const float K23 = 0.66666669f;               // a4/a6 ratio

    float a6[8], xr8[8];
    {
        const float4 A = *(const float4*)(att + c8);
        const float4 B = *(const float4*)(att + c8 + 4);
        a6[0] = 0.6f * LOG2E * A.x; a6[1] = 0.6f * LOG2E * A.y;
        a6[2] = 0.6f * LOG2E * A.z; a6[3] = 0.6f * LOG2E * A.w;
        a6[4] = 0.6f * LOG2E * B.x; a6[5] = 0.6f * LOG2E * B.y;
        a6[6] = 0.6f * LOG2E * B.z; a6[7] = 0.6f * LOG2E * B.w;
    }
    {
        const uint4 urv = *(const uint4*)(xr_bf + (size_t)i * 64 + sl * 4);
        xr8[0] = bflo(urv.x); xr8[1] = bfhi(urv.x);
        xr8[2] = bflo(urv.y); xr8[3] = bfhi(urv.y);
        xr8[4] = bflo(urv.z); xr8[5] = bfhi(urv.z);
        xr8[6] = bflo(urv.w); xr8[7] = bfhi(urv.w);
    }
    const int2 kr = rowptr2[i];     // per-quarter node range (deg >= 1: self-loop)
    int k = kr.x;
    const int kend = kr.y;

    float den = 0.f, b[8];
#pragma unroll
    for (int c = 0; c < 8; ++c) b[c] = 0.f;

    // 2-deep pipeline: gather for edge k+1 in flight while computing edge k
    uint4 u;
    {
        const int jv = srcs[k];
        u = *(const uint4*)(xl_bf + (size_t)jv * 64 + sl * 4);
    }
    for (; k < kend; ++k) {
        const uint4 ucur = u;
        {   // prefetch next (clamped; masked lanes don't issue)
            const int kn = (k + 1 < kend) ? (k + 1) : k;
            const int jn = srcs[kn];
            u = *(const uint4*)(xl_bf + (size_t)jn * 64 + sl * 4);
        }
        float t[8];
        t[0] = bflo(ucur.x) + xr8[0]; t[1] = bfhi(ucur.x) + xr8[1];
        t[2] = bflo(ucur.y) + xr8[2]; t[3] = bfhi(ucur.y) + xr8[3];
        t[4] = bflo(ucur.z) + xr8[4]; t[5] = bfhi(ucur.z) + xr8[5];
        t[6] = bflo(ucur.w) + xr8[6]; t[7] = bfhi(ucur.w) + xr8[7];
        float s = 0.f;
#pragma unroll
        for (int c = 0; c < 8; ++c) {
            const float h = fmaf(K23, fabsf(t[c]), t[c]);   // t + (2/3)|t|
            s = fmaf(a6[c], h, s);                           // 0.6*att*L2E*leaky
        }
        DPP_ADD(s, 0xB1);   // quad xor1
        DPP_ADD(s, 0x4E);   // quad xor2 -> 4-lane (one head) all-reduce
        const float p = __builtin_amdgcn_exp2f(s);
        den += p;
#pragma unroll
        for (int c = 0; c < 8; ++c) b[c] = fmaf(p, t[c], b[c]);
    }

    const float inv = 1.f / den;
    const float4 bbA = *(const float4*)(bias + c8);
    const float4 bbB = *(const float4*)(bias + c8 + 4);
    float4 o1, o2;
    o1.x = fmaf(b[0], inv, bbA.x - xr8[0]);
    o1.y = fmaf(b[1], inv, bbA.y - xr8[1]);
    o1.z = fmaf(b[2], inv, bbA.z - xr8[2]);
    o1.w = fmaf(b[3], inv, bbA.w - xr8[3]);
    o2.x = fmaf(b[4], inv, bbB.x - xr8[4]);
    o2.y = fmaf(b[5], inv, bbB.y - xr8[5]);
    o2.z = fmaf(b[6], inv, bbB.z - xr8[6]);
    o2.w = fmaf(b[7], inv, bbB.w - xr8[7]);
    *(float4*)(out + (size_t)i * TOT_CH + c8)     = o1;
    *(float4*)(out + (size_t)i * TOT_CH + c8 + 4) = o2;
}

// ================= launch =================
extern "C" void kernel_launch(void* const* d_in, const int* in_sizes, int n_in,
                              void* d_out, int out_size, void* d_ws, size_t ws_size,
                              hipStream_t stream) {
    const float* x    = (const float*)d_in[0];
    const int*   ei   = (const int*)d_in[1];
    const float* Wl   = (const float*)d_in[2];
    const float* Wr   = (const float*)d_in[3];
    const float* att  = (const float*)d_in[4];
    const float* bias = (const float*)d_in[5];
    float* out = (float*)d_out;
    char*  ws  = (char*)d_ws;

    unsigned* xl_bf = (unsigned*)(ws + OFF_XL);
    unsigned* ebuf  = (unsigned*)(ws + OFF_EBUF);
    unsigned* xr_bf = (unsigned*)(ws + OFF_XR);
    int*      ssrc  = (int*)(ws + OFF_SRC);
    unsigned* btg   = (unsigned*)(ws + OFF_BT);
    int*      gcur  = (int*)(ws + OFF_GCUR);
    int2*   rowptr2 = (int2*)(ws + OFF_ROWPTR);

    // K0: zero bucket cursors
    hipLaunchKernelGGL(zero_kernel, dim3(1), dim3(256), 0, stream, gcur);
    // K1: binscatter (208) || wconv (64)
    hipLaunchKernelGGL(k1_kernel, dim3(NBIN + 64), dim3(256), 0, stream,
                       Wl, Wr, btg, ei, gcur, ebuf);
    // K2: place (196, first) || gemm (782, x staged once per m-tile)
    hipLaunchKernelGGL(k2_kernel, dim3(NBUCK + MTILES), dim3(256), 0, stream,
                       x, btg, xl_bf, xr_bf, ebuf, gcur, rowptr2, ssrc);
    // K3: gat (one node per quarter-wave, 16 nodes/block)
    hipLaunchKernelGGL(gat_kernel, dim3(N_NODES / 16), dim3(256), 0, stream,
                       xl_bf, xr_bf, rowptr2, ssrc, att, bias, out);
}

// Round 18
// 81.941 us; speedup vs baseline: 1.0184x; 1.0184x over previous
//
#include <hip/hip_runtime.h>
#include <math.h>

#define N_NODES 50000
#define IN_CH   128
#define TOT_CH  128          // HEADS*OUT_CH
#define NEDGE   800000
#define ETOT    (NEDGE + N_NODES)
#define MTILES  ((N_NODES + 63) / 64)     // 782
#define NBUCK   ((N_NODES + 255) / 256)   // 196 buckets of 256 nodes
#define BCAP    8192                       // fixed slots per bucket (mean 4352, sigma 66)
#define EPB     4096                       // edges per binning block
#define NBIN    ((ETOT + EPB - 1) / EPB)   // 208
#define NT      8                          // src tiles (src>>13): 2MB of xl each

// ---------------- workspace layout (bytes) ----------------
#define OFF_XL      ((size_t)0)                 // bf16 [N][128] = 12.8MB
#define OFF_EBUF    ((size_t)12800000)          // u32 [NBUCK*BCAP] = 6.42MB
#define OFF_XR      ((size_t)25600000)          // bf16 [N][128] = 12.8MB
#define OFF_SRC     ((size_t)38400000)          // int [NBUCK*BCAP] = 6.42MB
#define OFF_BT      ((size_t)44900352)          // Bt bf16-pairs 64KB
#define OFF_GCUR    ((size_t)45000064)          // int [NBUCK]
#define OFF_ROWPTR  ((size_t)51200000)          // int2 [N] = 400KB

typedef float f32x4 __attribute__((ext_vector_type(4)));
typedef short s16x8 __attribute__((ext_vector_type(8)));

__device__ __forceinline__ unsigned f2bf(float f) {   // RNE f32->bf16 bits
    unsigned u = __float_as_uint(f);
    return (u + 0x7fffu + ((u >> 16) & 1u)) >> 16;
}
__device__ __forceinline__ float bflo(unsigned u) { return __uint_as_float(u << 16); }
__device__ __forceinline__ float bfhi(unsigned u) { return __uint_as_float(u & 0xffff0000u); }

__device__ __forceinline__ int SWZ(int row, int byteoff) {
    return row * 256 + (byteoff ^ ((row & 7) << 4));
}

// ============ K0: zero gcur ============
__global__ __launch_bounds__(256) void zero_kernel(int* __restrict__ gcur) {
    if (threadIdx.x < NBUCK) gcur[threadIdx.x] = 0;
}

// ============ K1: binscatter (fixed-capacity buckets) || wconv ============
__global__ __launch_bounds__(256) void k1_kernel(
    const float* __restrict__ Wl, const float* __restrict__ Wr,
    unsigned* __restrict__ btg, const int* __restrict__ ei,
    int* __restrict__ gcur, unsigned* __restrict__ ebuf)
{
    __shared__ int lcnt[256];
    __shared__ int lbase[256];
    const int bid = blockIdx.x;
    const int tid = threadIdx.x;

    if (bid < NBIN) {
        lcnt[tid] = 0;
        __syncthreads();
        const int base = bid * EPB;
        int sv[16], dv[16];
#pragma unroll
        for (int u = 0; u < 16; ++u) {
            const int e = base + u * 256 + tid;
            int s32 = 0, d32 = -1;
            if (e < ETOT) {
                if (e < NEDGE) { s32 = ei[e]; d32 = ei[NEDGE + e]; }
                else           { s32 = d32 = e - NEDGE; }
                atomicAdd(&lcnt[d32 >> 8], 1);
            }
            sv[u] = s32; dv[u] = d32;
        }
        __syncthreads();
        if (tid < NBUCK) {
            const int v = lcnt[tid];
            lbase[tid] = v ? atomicAdd(&gcur[tid], v) : 0;
        }
        __syncthreads();
        lcnt[tid] = 0;
        __syncthreads();
#pragma unroll
        for (int u = 0; u < 16; ++u) {
            const int d32 = dv[u];
            if (d32 >= 0) {
                const int b = d32 >> 8;
                const int p = lbase[b] + atomicAdd(&lcnt[b], 1);
                ebuf[b * BCAP + p] = (unsigned)sv[u] | ((unsigned)(d32 & 255) << 16);
            }
        }
    } else {
        const int g = (bid - NBIN) * 256 + tid;
        if (g < 256 * 64) {
            const int n = g >> 6, kk = g & 63;
            const float* W = (n < 128) ? Wl : Wr;
            const int nc = n & 127;
            const float a = W[(size_t)(2 * kk) * 128 + nc];
            const float b = W[(size_t)(2 * kk + 1) * 128 + nc];
            btg[g] = f2bf(a) | (f2bf(b) << 16);
        }
    }
}

// ============ K2: place (rank by node,src-tile) || MFMA GEMM ============
__global__ __launch_bounds__(256) void k2_kernel(
    const float* __restrict__ x, const unsigned* __restrict__ btg,
    unsigned* __restrict__ xl_bf, unsigned* __restrict__ xr_bf,
    const unsigned* __restrict__ ebuf, const int* __restrict__ gcur,
    int2* __restrict__ rowptr2, int* __restrict__ ssrc)
{
    __shared__ __align__(16) unsigned char smem[32768];
    __shared__ int wsum[4];
    const int bid = blockIdx.x;
    const int tid = threadIdx.x;

    if (bid < NBUCK) {
        // ---- place: per-(node,src-tile) ranking -> tile-sorted edge lists ----
        int* lcnt = (int*)smem;          // [256][NT] = 2048 ints
        const int ecnt  = gcur[bid];
        const int ebase = bid * BCAP;
        for (int t = tid; t < 256 * NT; t += 256) lcnt[t] = 0;
        __syncthreads();
        for (int k = tid; k < ecnt; k += 256) {
            const unsigned ed = ebuf[ebase + k];
            const int node = (ed >> 16) & 255;
            const int tile = (int)(ed & 0xffffu) >> 13;   // 0..NT-1
            atomicAdd(&lcnt[node * NT + tile], 1);
        }
        __syncthreads();
        // per-node serial scan over NT tiles -> node total v
        int v = 0;
        {
            int run = 0;
#pragma unroll
            for (int t = 0; t < NT; ++t) {
                const int tmp = lcnt[tid * NT + t];
                lcnt[tid * NT + t] = run;
                run += tmp;
            }
            v = run;
        }
        // block scan of node totals
        const int lane = tid & 63, wid = tid >> 6;
        int s = v;
#pragma unroll
        for (int off = 1; off < 64; off <<= 1) {
            int t = __shfl_up(s, off);
            if (lane >= off) s += t;
        }
        if (lane == 63) wsum[wid] = s;
        __syncthreads();
        if (tid == 0) {
            int acc = 0;
#pragma unroll
            for (int w = 0; w < 4; ++w) { int t = wsum[w]; wsum[w] = acc; acc += t; }
        }
        __syncthreads();
        const int P = wsum[wid] + s - v;              // exclusive node prefix
        const int node = (bid << 8) + tid;
        if (node < N_NODES) rowptr2[node] = make_int2(ebase + P, ebase + P + v);
#pragma unroll
        for (int t = 0; t < NT; ++t) lcnt[tid * NT + t] += ebase + P;   // -> cursors
        __syncthreads();
        for (int k = tid; k < ecnt; k += 256) {
            const unsigned ed = ebuf[ebase + k];
            const int nn = (ed >> 16) & 255;
            const int tile = (int)(ed & 0xffffu) >> 13;
            const int p = atomicAdd(&lcnt[nn * NT + tile], 1);
            ssrc[p] = (int)(ed & 0xffffu);
        }
        return;
    }

    // ---- gemm: one 64-row m-tile; loop over 4 n-subtiles (x staged ONCE) ----
    unsigned char* Al = smem;            // 16KB
    unsigned char* Bl = smem + 16384;    // 16KB (re-staged per n-tile)
    const int mt = bid - NBUCK;
    const int mbase = mt * 64;
    const int l  = tid & 63;
    const int wv = tid >> 6;

    {   // stage A (f32 -> bf16, swizzled) -- once
        const int r = tid >> 2, q = tid & 3;
        int gm = mbase + r;
        gm = (gm < N_NODES) ? gm : (N_NODES - 1);
        const float* xrow = x + (size_t)gm * IN_CH + q * 32;
#pragma unroll
        for (int i = 0; i < 8; ++i) {
            const float4 xv = *(const float4*)(xrow + i * 4);
            uint2 p;
            p.x = f2bf(xv.x) | (f2bf(xv.y) << 16);
            p.y = f2bf(xv.z) | (f2bf(xv.w) << 16);
            *(uint2*)(Al + SWZ(r, q * 64 + i * 8)) = p;
        }
    }
    {   // stage B tile 0
        const int r = tid >> 2, q = tid & 3;
        const unsigned* brow = btg + (size_t)r * 64 + q * 16;
#pragma unroll
        for (int i = 0; i < 4; ++i) {
            const uint4 v = *(const uint4*)(brow + i * 4);
            *(uint4*)(Bl + SWZ(r, q * 64 + i * 16)) = v;
        }
    }
    __syncthreads();

    s16x8 af[4];
#pragma unroll
    for (int ks = 0; ks < 4; ++ks)
        af[ks] = *(const s16x8*)(Al + SWZ(wv * 16 + (l & 15), ks * 64 + (l >> 4) * 16));

    for (int nt4 = 0; nt4 < 4; ++nt4) {
        f32x4 acc[4];
#pragma unroll
        for (int n = 0; n < 4; ++n) acc[n] = (f32x4){0.f, 0.f, 0.f, 0.f};
#pragma unroll
        for (int nsub = 0; nsub < 4; ++nsub) {
#pragma unroll
            for (int ks = 0; ks < 4; ++ks) {
                const s16x8 bfr = *(const s16x8*)(Bl + SWZ(nsub * 16 + (l & 15), ks * 64 + (l >> 4) * 16));
                acc[nsub] = __builtin_amdgcn_mfma_f32_16x16x32_bf16(af[ks], bfr, acc[nsub], 0, 0, 0);
            }
        }
        // epilogue for this 64-col tile
        unsigned* dstbuf = (nt4 < 2) ? xl_bf : xr_bf;
        const int ncol0 = (nt4 & 1) * 64;
#pragma unroll
        for (int nsub = 0; nsub < 4; ++nsub) {
            const int n = ncol0 + nsub * 16 + (l & 15);
#pragma unroll
            for (int reg = 0; reg < 4; ++reg) {
                const float v  = acc[nsub][reg];
                const float vp = __shfl_xor(v, 1);
                const int row = mbase + wv * 16 + (l >> 4) * 4 + reg;
                if (((l & 1) == 0) && row < N_NODES)
                    dstbuf[(size_t)row * 64 + (n >> 1)] = f2bf(v) | (f2bf(vp) << 16);
            }
        }
        if (nt4 == 3) break;
        __syncthreads();   // all waves done reading Bl
        {   // stage B tile nt4+1
            const int r = tid >> 2, q = tid & 3;
            const unsigned* brow = btg + (size_t)((nt4 + 1) * 64 + r) * 64 + q * 16;
#pragma unroll
            for (int i = 0; i < 4; ++i) {
                const uint4 v = *(const uint4*)(brow + i * 4);
                *(uint4*)(Bl + SWZ(r, q * 64 + i * 16)) = v;
            }
        }
        __syncthreads();
    }
}

// ================= K3: fused attention + aggregate =========
// One node per quarter-wave; edges arrive src-tile-sorted (L2-resident gathers).
#define DPP_ADD(s, ctrl) do { \
        int _t = __builtin_amdgcn_update_dpp(0, __float_as_int(s), ctrl, 0xf, 0xf, true); \
        s += __int_as_float(_t); } while(0)

__global__ __launch_bounds__(256) void gat_kernel(
    const unsigned* __restrict__ xl_bf, const unsigned* __restrict__ xr_bf,
    const int2* __restrict__ rowptr2, const int* __restrict__ srcs,
    const float* __restrict__ att, const float* __restrict__ bias,
    float* __restrict__ out)
{
    const int l  = threadIdx.x & 63;
    const int wv = threadIdx.x >> 6;
    const int sl = l & 15;                       // channel-group lane
    const int q  = l >> 4;                       // quarter = node slot
    const int i  = blockIdx.x * 16 + wv * 4 + q; // this quarter's node (grid exact)
    const int c8 = sl * 8;
    const float LOG2E = 1.4426950408889634f;
    const float K23 = 0.66666669f;               // a4/a6 ratio

    float a6[8], xr8[8];
    {
        const float4 A = *(const float4*)(att + c8);
        const float4 B = *(const float4*)(att + c8 + 4);
        a6[0] = 0.6f * LOG2E * A.x; a6[1] = 0.6f * LOG2E * A.y;
        a6[2] = 0.6f * LOG2E * A.z; a6[3] = 0.6f * LOG2E * A.w;
        a6[4] = 0.6f * LOG2E * B.x; a6[5] = 0.6f * LOG2E * B.y;
        a6[6] = 0.6f * LOG2E * B.z; a6[7] = 0.6f * LOG2E * B.w;
    }
    {
        const uint4 urv = *(const uint4*)(xr_bf + (size_t)i * 64 + sl * 4);
        xr8[0] = bflo(urv.x); xr8[1] = bfhi(urv.x);
        xr8[2] = bflo(urv.y); xr8[3] = bfhi(urv.y);
        xr8[4] = bflo(urv.z); xr8[5] = bfhi(urv.z);
        xr8[6] = bflo(urv.w); xr8[7] = bfhi(urv.w);
    }
    const int2 kr = rowptr2[i];     // per-quarter node range (deg >= 1: self-loop)
    int k = kr.x;
    const int kend = kr.y;

    float den = 0.f, b[8];
#pragma unroll
    for (int c = 0; c < 8; ++c) b[c] = 0.f;

    // 2-deep pipeline: gather for edge k+1 in flight while computing edge k
    uint4 u;
    {
        const int jv = srcs[k];
        u = *(const uint4*)(xl_bf + (size_t)jv * 64 + sl * 4);
    }
    for (; k < kend; ++k) {
        const uint4 ucur = u;
        {   // prefetch next (clamped; masked lanes don't issue)
            const int kn = (k + 1 < kend) ? (k + 1) : k;
            const int jn = srcs[kn];
            u = *(const uint4*)(xl_bf + (size_t)jn * 64 + sl * 4);
        }
        float t[8];
        t[0] = bflo(ucur.x) + xr8[0]; t[1] = bfhi(ucur.x) + xr8[1];
        t[2] = bflo(ucur.y) + xr8[2]; t[3] = bfhi(ucur.y) + xr8[3];
        t[4] = bflo(ucur.z) + xr8[4]; t[5] = bfhi(ucur.z) + xr8[5];
        t[6] = bflo(ucur.w) + xr8[6]; t[7] = bfhi(ucur.w) + xr8[7];
        float s = 0.f;
#pragma unroll
        for (int c = 0; c < 8; ++c) {
            const float h = fmaf(K23, fabsf(t[c]), t[c]);   // t + (2/3)|t|
            s = fmaf(a6[c], h, s);                           // 0.6*att*L2E*leaky
        }
        DPP_ADD(s, 0xB1);   // quad xor1
        DPP_ADD(s, 0x4E);   // quad xor2 -> 4-lane (one head) all-reduce
        const float p = __builtin_amdgcn_exp2f(s);
        den += p;
#pragma unroll
        for (int c = 0; c < 8; ++c) b[c] = fmaf(p, t[c], b[c]);
    }

    const float inv = 1.f / den;
    const float4 bbA = *(const float4*)(bias + c8);
    const float4 bbB = *(const float4*)(bias + c8 + 4);
    float4 o1, o2;
    o1.x = fmaf(b[0], inv, bbA.x - xr8[0]);
    o1.y = fmaf(b[1], inv, bbA.y - xr8[1]);
    o1.z = fmaf(b[2], inv, bbA.z - xr8[2]);
    o1.w = fmaf(b[3], inv, bbA.w - xr8[3]);
    o2.x = fmaf(b[4], inv, bbB.x - xr8[4]);
    o2.y = fmaf(b[5], inv, bbB.y - xr8[5]);
    o2.z = fmaf(b[6], inv, bbB.z - xr8[6]);
    o2.w = fmaf(b[7], inv, bbB.w - xr8[7]);
    *(float4*)(out + (size_t)i * TOT_CH + c8)     = o1;
    *(float4*)(out + (size_t)i * TOT_CH + c8 + 4) = o2;
}

// ================= launch =================
extern "C" void kernel_launch(void* const* d_in, const int* in_sizes, int n_in,
                              void* d_out, int out_size, void* d_ws, size_t ws_size,
                              hipStream_t stream) {
    const float* x    = (const float*)d_in[0];
    const int*   ei   = (const int*)d_in[1];
    const float* Wl   = (const float*)d_in[2];
    const float* Wr   = (const float*)d_in[3];
    const float* att  = (const float*)d_in[4];
    const float* bias = (const float*)d_in[5];
    float* out = (float*)d_out;
    char*  ws  = (char*)d_ws;

    unsigned* xl_bf = (unsigned*)(ws + OFF_XL);
    unsigned* ebuf  = (unsigned*)(ws + OFF_EBUF);
    unsigned* xr_bf = (unsigned*)(ws + OFF_XR);
    int*      ssrc  = (int*)(ws + OFF_SRC);
    unsigned* btg   = (unsigned*)(ws + OFF_BT);
    int*      gcur  = (int*)(ws + OFF_GCUR);
    int2*   rowptr2 = (int2*)(ws + OFF_ROWPTR);

    // K0: zero bucket cursors
    hipLaunchKernelGGL(zero_kernel, dim3(1), dim3(256), 0, stream, gcur);
    // K1: binscatter (208) || wconv (64)
    hipLaunchKernelGGL(k1_kernel, dim3(NBIN + 64), dim3(256), 0, stream,
                       Wl, Wr, btg, ei, gcur, ebuf);
    // K2: place (196, tile-ranked) || gemm (782)
    hipLaunchKernelGGL(k2_kernel, dim3(NBUCK + MTILES), dim3(256), 0, stream,
                       x, btg, xl_bf, xr_bf, ebuf, gcur, rowptr2, ssrc);
    // K3: gat (one node per quarter-wave; src-tile-sorted edge lists)
    hipLaunchKernelGGL(gat_kernel, dim3(N_NODES / 16), dim3(256), 0, stream,
                       xl_bf, xr_bf, rowptr2, ssrc, att, bias, out);
}